// Round 2
// baseline (263.619 us; speedup 1.0000x reference)
//
#include <hip/hip_runtime.h>
#include <math.h>

#define B_   32
#define N_   128
#define H_   100
#define VT   8          // v rows per block
#define TPB  448        // 8 v * 50 h-pairs = 400 active lanes
#define ROWS (B_ * N_)  // 4096

// ---------------------------------------------------------------------------
// K0: node_mask[row] = (sum of edges[row, :, :] != 0). One wave per row.
__global__ __launch_bounds__(256) void k_mask(const float* __restrict__ edges,
                                              float* __restrict__ nmask) {
    const int t = threadIdx.x, lane = t & 63, wv = t >> 6;
    const int row = blockIdx.x * 4 + wv;                 // grid = 1024
    const float4* eg = (const float4*)(edges + (size_t)row * N_ * 4);  // 128 f4
    float4 e0 = eg[lane], e1 = eg[lane + 64];
    float s = ((e0.x + e0.y) + (e0.z + e0.w)) + ((e1.x + e1.y) + (e1.z + e1.w));
#pragma unroll
    for (int off = 32; off > 0; off >>= 1) s += __shfl_down(s, off);
    if (lane == 0) nmask[row] = (s != 0.f) ? 1.f : 0.f;
}

// ---------------------------------------------------------------------------
// K1: initial projections hv = nodes@Wv, hw = nodes@Ww  (pass 0 inputs)
__global__ __launch_bounds__(TPB) void k_proj0(const float* __restrict__ nodes,
                                               const float* __restrict__ Wv,
                                               const float* __restrict__ Ww,
                                               float* __restrict__ hv_out,
                                               float* __restrict__ hw_out) {
    __shared__ float hid_s[VT * H_];                     // 3.2 KB
    const int b = blockIdx.y, v0 = blockIdx.x * VT;
    const int t = threadIdx.x, v = t / 50, hp = t % 50;
    const bool act = (v < VT);
    const int row = b * N_ + v0 + (act ? v : 0);

    const float4* ng = (const float4*)(nodes + (size_t)(b * N_ + v0) * H_);
    for (int idx = t; idx < VT * 25; idx += TPB) ((float4*)hid_s)[idx] = ng[idx];
    __syncthreads();
    if (!act) return;

    const float2* Wv2 = (const float2*)Wv;
    const float2* Ww2 = (const float2*)Ww;
    float va0 = 0, va1 = 0, wa0 = 0, wa1 = 0;
    const float* hr = hid_s + v * H_;
#pragma unroll 4
    for (int k = 0; k < H_; ++k) {
        const float hk = hr[k];
        const float2 wv = Wv2[k * 50 + hp];
        const float2 ww = Ww2[k * 50 + hp];
        va0 = fmaf(hk, wv.x, va0); va1 = fmaf(hk, wv.y, va1);
        wa0 = fmaf(hk, ww.x, wa0); wa1 = fmaf(hk, ww.y, wa1);
    }
    *(float2*)(hv_out + (size_t)row * H_ + hp * 2) = make_float2(va0, va1);
    *(float2*)(hw_out + (size_t)row * H_ + hp * 2) = make_float2(wa0, wa1);
}

// ---------------------------------------------------------------------------
// K2: one full message pass, fused:
//   messages (LDS-staged hw + edges) -> tanh update -> next pass's hv/hw.
// hv is block-private across passes (single buffer); hw crosses blocks
// within a batch, so it is double-buffered (hw_in != hw_out).
__global__ __launch_bounds__(TPB) void k_pass(const float* __restrict__ edges,
                                              const float* __restrict__ Wv,
                                              const float* __restrict__ Ww,
                                              const float* __restrict__ We,
                                              const float* __restrict__ Wu,
                                              const float* hv_io,
                                              const float* __restrict__ hw_in,
                                              float* __restrict__ hw_out,
                                              float* __restrict__ hidden,
                                              const float* __restrict__ nmask,
                                              int do_proj) {
    __shared__ float  hw_s[64 * H_];       // 25.6 KB (reused as hid_new for proj)
    __shared__ float4 e_s[VT * 64];        // 8 KB    (reused as msg_s)
    __shared__ float  mask_s[VT * 64];     // 2 KB
    __shared__ float  hid_s[VT * H_];      // 3.2 KB  (pre-update hidden tile)

    const int b = blockIdx.y, v0 = blockIdx.x * VT;
    const int t = threadIdx.x, v = t / 50, hp = t % 50;
    const bool act = (v < VT);
    const int row = b * N_ + v0 + (act ? v : 0);

    float2 hv2 = make_float2(0.f, 0.f), we0, we1, we2, we3;
    if (act) {
        hv2 = *(const float2*)(hv_io + (size_t)row * H_ + hp * 2);
        we0 = *(const float2*)(We + 0 * H_ + hp * 2);
        we1 = *(const float2*)(We + 1 * H_ + hp * 2);
        we2 = *(const float2*)(We + 2 * H_ + hp * 2);
        we3 = *(const float2*)(We + 3 * H_ + hp * 2);
    }
    float a0 = 0.f, a1 = 0.f;

    for (int half = 0; half < 2; ++half) {
        const int w0 = half * 64;
        __syncthreads();   // protect LDS from previous iteration's readers
        {   // stage hw rows [w0, w0+64) : 1600 float4
            const float4* hwg = (const float4*)(hw_in + (size_t)(b * N_ + w0) * H_);
            float4* hws4 = (float4*)hw_s;
            for (int idx = t; idx < 64 * 25; idx += TPB) hws4[idx] = hwg[idx];
        }
        {   // stage edges tile + per-edge mask : VT*64 float4
            const float4* eg = (const float4*)edges;
            for (int idx = t; idx < VT * 64; idx += TPB) {
                const int vv = idx >> 6, w = idx & 63;
                const float4 e = eg[(size_t)(b * N_ + v0 + vv) * N_ + w0 + w];
                e_s[vv * 64 + w] = e;
                const float s = ((e.x + e.y) + (e.z + e.w));
                mask_s[vv * 64 + w] = (s != 0.f) ? 1.f : 0.f;
            }
        }
        if (half == 0) {   // stage this block's pre-update hidden rows (once)
            const float4* hg = (const float4*)(hidden + (size_t)(b * N_ + v0) * H_);
            for (int idx = t; idx < VT * 25; idx += TPB) ((float4*)hid_s)[idx] = hg[idx];
        }
        __syncthreads();
        if (act) {
            const float4* ev = e_s + v * 64;
            const float*  mv = mask_s + v * 64;
#pragma unroll 4
            for (int w = 0; w < 64; ++w) {
                const float4 e = ev[w];
                const float  m = mv[w];
                const float2 hw2 = *(const float2*)(hw_s + w * H_ + hp * 2);
                float p0 = hv2.x + hw2.x, p1 = hv2.y + hw2.y;
                p0 = fmaf(e.x, we0.x, p0); p1 = fmaf(e.x, we0.y, p1);
                p0 = fmaf(e.y, we1.x, p0); p1 = fmaf(e.y, we1.y, p1);
                p0 = fmaf(e.z, we2.x, p0); p1 = fmaf(e.z, we2.y, p1);
                p0 = fmaf(e.w, we3.x, p0); p1 = fmaf(e.w, we3.y, p1);
                a0 = fmaf(m, fmaxf(p0, 0.f), a0);
                a1 = fmaf(m, fmaxf(p1, 0.f), a1);
            }
        }
    }

    __syncthreads();                        // all e_s / hw_s readers done
    float* msg_s = (float*)e_s;             // reuse: VT*H floats = 3.2 KB
    if (act) *(float2*)(msg_s + v * H_ + hp * 2) = make_float2(a0, a1);
    __syncthreads();

    // update: u = [hid, msg] @ Wu ; hidden = mask ? tanh(u) : hid
    float2 nh = make_float2(0.f, 0.f);
    if (act) {
        const float2* Wu2 = (const float2*)Wu;
        float u0 = 0.f, u1 = 0.f;
        const float* hr = hid_s + v * H_;
        const float* mr = msg_s + v * H_;
#pragma unroll 4
        for (int k = 0; k < H_; ++k) {
            const float hk = hr[k];
            const float2 wu = Wu2[k * 50 + hp];
            u0 = fmaf(hk, wu.x, u0); u1 = fmaf(hk, wu.y, u1);
        }
#pragma unroll 4
        for (int k = 0; k < H_; ++k) {
            const float mk = mr[k];
            const float2 wu = Wu2[(H_ + k) * 50 + hp];
            u0 = fmaf(mk, wu.x, u0); u1 = fmaf(mk, wu.y, u1);
        }
        const float nm = nmask[row];
        const float h0 = hr[hp * 2], h1 = hr[hp * 2 + 1];
        nh.x = (nm != 0.f) ? tanhf(u0) : h0;
        nh.y = (nm != 0.f) ? tanhf(u1) : h1;
        *(float2*)(hidden + (size_t)row * H_ + hp * 2) = nh;
    }

    if (do_proj) {   // next pass's hv/hw from the fresh hidden (block's own rows)
        float* hn_s = hw_s;                 // reuse 25.6 KB region
        __syncthreads();                    // hw_s readers long done; order hn writes
        if (act) *(float2*)(hn_s + v * H_ + hp * 2) = nh;
        __syncthreads();
        if (act) {
            const float2* Wv2 = (const float2*)Wv;
            const float2* Ww2 = (const float2*)Ww;
            float va0 = 0, va1 = 0, wa0 = 0, wa1 = 0;
            const float* hr = hn_s + v * H_;
#pragma unroll 4
            for (int k = 0; k < H_; ++k) {
                const float hk = hr[k];
                const float2 wv = Wv2[k * 50 + hp];
                const float2 ww = Ww2[k * 50 + hp];
                va0 = fmaf(hk, wv.x, va0); va1 = fmaf(hk, wv.y, va1);
                wa0 = fmaf(hk, ww.x, wa0); wa1 = fmaf(hk, ww.y, wa1);
            }
            *(float2*)((float*)hv_io + (size_t)row * H_ + hp * 2) = make_float2(va0, va1);
            *(float2*)(hw_out + (size_t)row * H_ + hp * 2) = make_float2(wa0, wa1);
        }
    }
}

// ---------------------------------------------------------------------------
// K3: readout. graph_terms = relu([hidden, nodes] @ Wr), masked sum over v.
__global__ __launch_bounds__(TPB) void k_readout(const float* __restrict__ hidden,
                                                 const float* __restrict__ nodes,
                                                 const float* __restrict__ Wr,
                                                 const float* __restrict__ nmask,
                                                 float* __restrict__ out) {
    __shared__ float hid_s[VT * H_], nod_s[VT * H_], red_s[VT * H_];  // 9.6 KB
    const int b = blockIdx.y, v0 = blockIdx.x * VT;
    const int t = threadIdx.x, v = t / 50, hp = t % 50;
    const bool act = (v < VT);
    const int row = b * N_ + v0 + (act ? v : 0);

    const float4* hg = (const float4*)(hidden + (size_t)(b * N_ + v0) * H_);
    const float4* ng = (const float4*)(nodes + (size_t)(b * N_ + v0) * H_);
    for (int idx = t; idx < VT * 25; idx += TPB) ((float4*)hid_s)[idx] = hg[idx];
    for (int idx = t; idx < VT * 25; idx += TPB) ((float4*)nod_s)[idx] = ng[idx];
    __syncthreads();

    if (act) {
        const float2* Wr2 = (const float2*)Wr;
        float u0 = 0.f, u1 = 0.f;
        const float* hr = hid_s + v * H_;
        const float* nr = nod_s + v * H_;
#pragma unroll 4
        for (int k = 0; k < H_; ++k) {
            const float hk = hr[k];
            const float2 wr = Wr2[k * 50 + hp];
            u0 = fmaf(hk, wr.x, u0); u1 = fmaf(hk, wr.y, u1);
        }
#pragma unroll 4
        for (int k = 0; k < H_; ++k) {
            const float nk = nr[k];
            const float2 wr = Wr2[(H_ + k) * 50 + hp];
            u0 = fmaf(nk, wr.x, u0); u1 = fmaf(nk, wr.y, u1);
        }
        const float m = nmask[row];
        red_s[v * H_ + hp * 2]     = m * fmaxf(u0, 0.f);
        red_s[v * H_ + hp * 2 + 1] = m * fmaxf(u1, 0.f);
    }
    __syncthreads();
    if (t < H_) {
        float s = 0.f;
#pragma unroll
        for (int vv = 0; vv < VT; ++vv) s += red_s[vv * H_ + t];
        atomicAdd(out + b * H_ + t, s);
    }
}

// ---------------------------------------------------------------------------
extern "C" void kernel_launch(void* const* d_in, const int* in_sizes, int n_in,
                              void* d_out, int out_size, void* d_ws, size_t ws_size,
                              hipStream_t stream) {
    const float* nodes = (const float*)d_in[0];
    const float* edges = (const float*)d_in[1];
    const float* Wv    = (const float*)d_in[2];
    const float* Ww    = (const float*)d_in[3];
    const float* We    = (const float*)d_in[4];
    const float* Wu    = (const float*)d_in[5];
    const float* Wr    = (const float*)d_in[6];
    float* out = (float*)d_out;

    const size_t RH = (size_t)ROWS * H_;
    float* hidden = (float*)d_ws;        // 409600
    float* hv     = hidden + RH;         // 409600 (block-private across passes)
    float* hwA    = hv + RH;             // 409600
    float* hwB    = hwA + RH;            // 409600
    float* nmask  = hwB + RH;            // 4096

    hipMemcpyAsync(hidden, nodes, RH * sizeof(float), hipMemcpyDeviceToDevice, stream);
    hipMemsetAsync(d_out, 0, (size_t)out_size * sizeof(float), stream);

    const dim3 grid(N_ / VT, B_);        // (16, 32) = 512 blocks
    k_mask<<<ROWS / 4, 256, 0, stream>>>(edges, nmask);
    k_proj0<<<grid, TPB, 0, stream>>>(nodes, Wv, Ww, hv, hwA);
    k_pass<<<grid, TPB, 0, stream>>>(edges, Wv, Ww, We, Wu, hv, hwA, hwB, hidden, nmask, 1);
    k_pass<<<grid, TPB, 0, stream>>>(edges, Wv, Ww, We, Wu, hv, hwB, hwA, hidden, nmask, 1);
    k_pass<<<grid, TPB, 0, stream>>>(edges, Wv, Ww, We, Wu, hv, hwA, hwB, hidden, nmask, 0);
    k_readout<<<grid, TPB, 0, stream>>>(hidden, nodes, Wr, nmask, out);
}